// Round 1
// baseline (2813.516 us; speedup 1.0000x reference)
//
#include <hip/hip_runtime.h>
#include <hip/hip_bf16.h>

// Problem: GlobalAttention  Q_LEN=512, SRC_LEN=2048, B=32, D=1024, F=2048
// query  [512,32,1024] f32    -> rows r=q*32+b, contiguous d
// values [2048,32,1024] f32   -> rows s*32+b, contiguous v
// W1 [1024,1024], b1[1024], W2 [1024,2048], b2[1024]
// out [512,32,1024] f32

#define BM 128
#define BN 128
#define BK 16

// Tiled fp32 GEMM.
// NT==true : C[m,n] = sum_k A[m*lda+k] * B[n*ldb+k]      (both K-contiguous)
// NT==false: C[m,n] = sum_k A[m*lda+k] * B[k*ldb+n]      (B N-contiguous)
// A2/Ksplit: if A2 != null, k >= Ksplit reads A2[m*lda + (k-Ksplit)] (concat along K)
// MODE: 0 = plain, 1 = +bias[n], 2 = tanh(x + bias[n])
// blockIdx.z batching via element strides sAb/sBb/sCb.
template<bool NT, int MODE>
__global__ __launch_bounds__(256) void gemm_f32(
    const float* __restrict__ A, const float* __restrict__ A2, int Ksplit,
    const float* __restrict__ Bm, const float* __restrict__ bias,
    float* __restrict__ C,
    long lda, long ldb, long ldc, int K,
    long sAb, long sBb, long sCb)
{
    __shared__ float As[BK][BM + 4];
    __shared__ float Bs[BK][BN + 4];

    const int bz = blockIdx.z;
    const float* Ab  = A + (long)bz * sAb;
    const float* A2b = A2 ? (A2 + (long)bz * sAb) : nullptr;
    const float* Bb  = Bm + (long)bz * sBb;
    float*       Cb  = C + (long)bz * sCb;

    const int m0 = blockIdx.y * BM;
    const int n0 = blockIdx.x * BN;
    const int t  = threadIdx.x;
    const int tx = t & 15;        // 0..15 -> col group
    const int ty = t >> 4;        // 0..15 -> row group

    float acc[8][8];
#pragma unroll
    for (int i = 0; i < 8; ++i)
#pragma unroll
        for (int j = 0; j < 8; ++j) acc[i][j] = 0.f;

    for (int k0 = 0; k0 < K; k0 += BK) {
        // ---- A tile: 128 rows x 16 k (K-contiguous), store transposed As[k][row]
        const float* Asrc = (A2b && k0 >= Ksplit) ? (A2b - Ksplit) : Ab;
#pragma unroll
        for (int c = 0; c < 2; ++c) {
            int chunk = t + c * 256;          // 0..511
            int row = chunk >> 2;             // 0..127
            int kq  = chunk & 3;              // 0..3  (float4 within the 16 k's)
            float4 v = *(const float4*)(Asrc + (long)(m0 + row) * lda + k0 + kq * 4);
            As[kq * 4 + 0][row] = v.x;
            As[kq * 4 + 1][row] = v.y;
            As[kq * 4 + 2][row] = v.z;
            As[kq * 4 + 3][row] = v.w;
        }
        if (NT) {
            // B tile: 128 n-rows x 16 k, store transposed Bs[k][n]
#pragma unroll
            for (int c = 0; c < 2; ++c) {
                int chunk = t + c * 256;
                int row = chunk >> 2;
                int kq  = chunk & 3;
                float4 v = *(const float4*)(Bb + (long)(n0 + row) * ldb + k0 + kq * 4);
                Bs[kq * 4 + 0][row] = v.x;
                Bs[kq * 4 + 1][row] = v.y;
                Bs[kq * 4 + 2][row] = v.z;
                Bs[kq * 4 + 3][row] = v.w;
            }
        } else {
            // B tile: 16 k-rows x 128 n (N-contiguous): direct float4 into Bs[k][n]
#pragma unroll
            for (int c = 0; c < 2; ++c) {
                int chunk = t + c * 256;      // 512 chunks = 16 k * 32 float4
                int kr = chunk >> 5;          // 0..15
                int vq = chunk & 31;          // 0..31
                float4 v = *(const float4*)(Bb + (long)(k0 + kr) * ldb + n0 + vq * 4);
                *(float4*)&Bs[kr][vq * 4] = v;
            }
        }
        __syncthreads();

#pragma unroll
        for (int k = 0; k < BK; ++k) {
            float4 a0 = *(const float4*)&As[k][ty * 8];
            float4 a1 = *(const float4*)&As[k][ty * 8 + 4];
            float4 b0 = *(const float4*)&Bs[k][tx * 8];
            float4 b1 = *(const float4*)&Bs[k][tx * 8 + 4];
            float ar[8] = {a0.x, a0.y, a0.z, a0.w, a1.x, a1.y, a1.z, a1.w};
            float br[8] = {b0.x, b0.y, b0.z, b0.w, b1.x, b1.y, b1.z, b1.w};
#pragma unroll
            for (int i = 0; i < 8; ++i)
#pragma unroll
                for (int j = 0; j < 8; ++j)
                    acc[i][j] += ar[i] * br[j];
        }
        __syncthreads();
    }

    // ---- epilogue
    float brow[8];
    if (MODE >= 1) {
#pragma unroll
        for (int j = 0; j < 8; ++j) brow[j] = bias[n0 + tx * 8 + j];
    }
#pragma unroll
    for (int i = 0; i < 8; ++i) {
        long row = m0 + ty * 8 + i;
        float v[8];
#pragma unroll
        for (int j = 0; j < 8; ++j) {
            float x = acc[i][j];
            if (MODE >= 1) x += brow[j];
            if (MODE == 2) x = tanhf(x);
            v[j] = x;
        }
        float4* dst = (float4*)&Cb[row * ldc + n0 + tx * 8];
        dst[0] = make_float4(v[0], v[1], v[2], v[3]);
        dst[1] = make_float4(v[4], v[5], v[6], v[7]);
    }
}

// softmax over rows of length 2048, in place. One block (256 thr) per row.
__global__ __launch_bounds__(256) void softmax2048(float* __restrict__ S)
{
    __shared__ float red[4];
    float* p = S + (long)blockIdx.x * 2048 + threadIdx.x * 8;
    float4 a = ((float4*)p)[0];
    float4 b = ((float4*)p)[1];

    float m = fmaxf(fmaxf(fmaxf(a.x, a.y), fmaxf(a.z, a.w)),
                    fmaxf(fmaxf(b.x, b.y), fmaxf(b.z, b.w)));
#pragma unroll
    for (int off = 32; off; off >>= 1) m = fmaxf(m, __shfl_xor(m, off));
    int wid = threadIdx.x >> 6;
    if ((threadIdx.x & 63) == 0) red[wid] = m;
    __syncthreads();
    m = fmaxf(fmaxf(red[0], red[1]), fmaxf(red[2], red[3]));
    __syncthreads();

    a.x = __expf(a.x - m); a.y = __expf(a.y - m);
    a.z = __expf(a.z - m); a.w = __expf(a.w - m);
    b.x = __expf(b.x - m); b.y = __expf(b.y - m);
    b.z = __expf(b.z - m); b.w = __expf(b.w - m);

    float s = a.x + a.y + a.z + a.w + b.x + b.y + b.z + b.w;
#pragma unroll
    for (int off = 32; off; off >>= 1) s += __shfl_xor(s, off);
    if ((threadIdx.x & 63) == 0) red[wid] = s;
    __syncthreads();
    s = red[0] + red[1] + red[2] + red[3];
    float inv = 1.0f / s;

    a.x *= inv; a.y *= inv; a.z *= inv; a.w *= inv;
    b.x *= inv; b.y *= inv; b.z *= inv; b.w *= inv;
    ((float4*)p)[0] = a;
    ((float4*)p)[1] = b;
}

extern "C" void kernel_launch(void* const* d_in, const int* in_sizes, int n_in,
                              void* d_out, int out_size, void* d_ws, size_t ws_size,
                              hipStream_t stream)
{
    const float* query  = (const float*)d_in[0];
    const float* values = (const float*)d_in[1];
    const float* W1     = (const float*)d_in[2];
    const float* b1     = (const float*)d_in[3];
    const float* W2     = (const float*)d_in[4];
    const float* b2     = (const float*)d_in[5];
    float* out = (float*)d_out;

    const int Bc = 32, QL = 512, SL = 2048, D = 1024;
    const long R = (long)QL * Bc;                 // 16384

    float* qr = (float*)d_ws;                     // [R][D] = 67 MB (later reused for attended)
    size_t qrBytes = (size_t)R * D * sizeof(float);
    float* sc = (float*)((char*)d_ws + qrBytes);  // [grp][QL][SL]
    size_t scPerB = (size_t)QL * SL * sizeof(float);

    int grp = 32;
    if (ws_size < qrBytes + 32 * scPerB) {
        size_t avail = ws_size > qrBytes ? ws_size - qrBytes : 0;
        grp = (int)(avail / scPerB);
        if (grp < 1)  grp = 1;
        if (grp > 32) grp = 32;
    }

    // K1: qr[r,v] = query[r,:] . W1[v,:] + b1[v]      (M=16384,N=1024,K=1024)
    {
        dim3 g(D / BN, R / BM, 1);
        gemm_f32<true, 1><<<g, 256, 0, stream>>>(
            query, nullptr, 1 << 30, W1, b1, qr,
            D, D, D, D, 0, 0, 0);
    }

    for (int b0 = 0; b0 < Bc; b0 += grp) {
        int g = (Bc - b0 < grp) ? (Bc - b0) : grp;

        // K2: sc[b,q,s] = qr[(q*32+b),:] . values[(s*32+b),:]   (M=512,N=2048,K=1024)
        {
            dim3 gd(SL / BN, QL / BM, g);
            gemm_f32<true, 0><<<gd, 256, 0, stream>>>(
                qr + (size_t)b0 * D, nullptr, 1 << 30,
                values + (size_t)b0 * D, nullptr, sc,
                (long)Bc * D, (long)Bc * D, SL, D,
                D, D, (long)QL * SL);
        }
        // K3: softmax rows
        softmax2048<<<g * QL, 256, 0, stream>>>(sc);

        // K4: attended[(q*32+b),v] = sum_s sc[b,q,s] * values[(s*32+b),v]
        //     (M=512,N=1024,K=2048)  B is N-contiguous -> NN. Writes over qr.
        {
            dim3 gd(D / BN, QL / BM, g);
            gemm_f32<false, 0><<<gd, 256, 0, stream>>>(
                sc, nullptr, 1 << 30,
                values + (size_t)b0 * D, nullptr, qr + (size_t)b0 * D,
                SL, (long)Bc * D, (long)Bc * D, SL,
                (long)QL * SL, D, D);
        }
    }

    // K5: out[r,o] = tanh( attended[r,:].W2[o,0:1024] + query[r,:].W2[o,1024:2048] + b2[o] )
    {
        dim3 g(D / BN, R / BM, 1);
        gemm_f32<true, 2><<<g, 256, 0, stream>>>(
            qr, query, D, W2, b2, out,
            D, 2048, D, 2048, 0, 0, 0);
    }
}

// Round 2
// 973.421 us; speedup vs baseline: 2.8903x; 2.8903x over previous
//
#include <hip/hip_runtime.h>
#include <hip/hip_bf16.h>

// GlobalAttention: Q_LEN=512, SRC_LEN=2048, B=32, D=1024, F=2048
// Fast path: split-bf16 (hi+lo) MFMA GEMMs.
//   K1: qr = query.W1^T + b1           split(3-term), writes qr as bf16 pair
//   K2: scores[b,q,s] = qr . values    split(3-term), f32 out
//   SM: softmax rows -> P (bf16)
//   K4: att = P . V^T (vT pre-transposed)  pure bf16, writes att as bf16 pair
//   K5: out = tanh([att,query].W2^T + b2)  split(3-term), concat-K
// Fallback (ws too small): round-1 fp32 VALU pipeline.

typedef __attribute__((ext_vector_type(8))) short bf16x8;
typedef __attribute__((ext_vector_type(4))) float f32x4;

__device__ __forceinline__ ushort f2bf(float x) {
    unsigned u = __builtin_bit_cast(unsigned, x);
    u += 0x7FFFu + ((u >> 16) & 1u);
    return (ushort)(u >> 16);
}
__device__ __forceinline__ float bf2f(ushort h) {
    unsigned u = (unsigned)h << 16;
    return __builtin_bit_cast(float, u);
}

__device__ __forceinline__ void async16(const ushort* g, ushort* l) {
    __builtin_amdgcn_global_load_lds(
        (const __attribute__((address_space(1))) unsigned int*)g,
        (__attribute__((address_space(3))) unsigned int*)l, 16, 0, 0);
}

// ---------------------------------------------------------------------------
// MFMA GEMM: C[m,n] = sum_k A[m,k]*B[n,k]  (NT; all tiles K-contiguous rows)
// 128x128 tile, BK=32, 4 waves each 64x64 (4x4 frags of 16x16x32).
// SPLIT: A/B given as hi/lo bf16 pairs, 3-term accumulation.
// CONCAT: k >= Ksplit reads A2 (k-Ksplit).
// OUTMODE: 0=f32, 1=f32+bias, 2=bf16 split pair out (+bias if given), 3=tanh(x+bias) f32
// LDS layout: linear [row][32] bf16 per tile, 16B-slot index XOR-swizzled by
// ((row>>1)&3) on BOTH the global source (staging) and the frag read.
// ---------------------------------------------------------------------------
template<bool SPLIT, bool CONCAT, int OUTMODE>
__global__ __launch_bounds__(256, 2) void gemm_bf16_mfma(
    const ushort* __restrict__ Ahi, const ushort* __restrict__ Alo,
    const ushort* __restrict__ A2hi, const ushort* __restrict__ A2lo, int Ksplit,
    const ushort* __restrict__ Bhi, const ushort* __restrict__ Blo,
    const float* __restrict__ bias,
    float* __restrict__ Cf, ushort* __restrict__ Chi, ushort* __restrict__ Clo,
    long lda, long ldb, long ldc, int K,
    long sAb, long sBb, long sCb)
{
    __shared__ ushort lds[(SPLIT ? 4 : 2) * 4096];
    ushort* sA0 = lds;
    ushort* sB0 = lds + 4096;
    ushort* sA1 = SPLIT ? (lds + 8192) : nullptr;
    ushort* sB1 = SPLIT ? (lds + 12288) : nullptr;

    const int t   = threadIdx.x;
    const int l   = t & 63;
    const int wid = t >> 6;
    const int wm  = (wid >> 1) * 64;
    const int wn  = (wid & 1) * 64;
    const int lr  = l & 15;
    const int lkp = ((l >> 4) ^ ((lr >> 1) & 3)) * 8;   // swizzled K-slot (elements)

    const long m0 = (long)blockIdx.y * 128;
    const long n0 = (long)blockIdx.x * 128;
    const int  bz = blockIdx.z;

    const ushort* Ah = Ahi + (long)bz * sAb;
    const ushort* Al = SPLIT ? (Alo + (long)bz * sAb) : nullptr;
    const ushort* Bh = Bhi + (long)bz * sBb;
    const ushort* Bl = SPLIT ? (Blo + (long)bz * sBb) : nullptr;

    // staging geometry: thread t covers chunks t (rows 0..63) and t+256 (rows 64..127)
    const int r0 = t >> 2, q = t & 3;
    const int qs = q ^ ((r0 >> 1) & 3);    // same for r0+64 since +64 keeps (r>>1)&3
    const long eA0 = (m0 + r0)      * lda + qs * 8;
    const long eA1 = (m0 + r0 + 64) * lda + qs * 8;
    const long eB0 = (n0 + r0)      * ldb + qs * 8;
    const long eB1 = (n0 + r0 + 64) * ldb + qs * 8;
    const int o0 = t * 8, o1 = (t + 256) * 8;

    const f32x4 zero = {0.f, 0.f, 0.f, 0.f};
    f32x4 acc[4][4];
#pragma unroll
    for (int i = 0; i < 4; ++i)
#pragma unroll
        for (int j = 0; j < 4; ++j) acc[i][j] = zero;

    for (int k0 = 0; k0 < K; k0 += 32) {
        const ushort *aHk, *aLk;
        if (CONCAT && k0 >= Ksplit) {
            aHk = A2hi + (k0 - Ksplit);
            aLk = SPLIT ? (A2lo + (k0 - Ksplit)) : nullptr;
        } else {
            aHk = Ah + k0;
            aLk = SPLIT ? (Al + k0) : nullptr;
        }
        const ushort* bHk = Bh + k0;
        const ushort* bLk = SPLIT ? (Bl + k0) : nullptr;

        async16(aHk + eA0, sA0 + o0);
        async16(aHk + eA1, sA0 + o1);
        async16(bHk + eB0, sB0 + o0);
        async16(bHk + eB1, sB0 + o1);
        if (SPLIT) {
            async16(aLk + eA0, sA1 + o0);
            async16(aLk + eA1, sA1 + o1);
            async16(bLk + eB0, sB1 + o0);
            async16(bLk + eB1, sB1 + o1);
        }
        __syncthreads();   // compiler emits vmcnt(0) drain before barrier

        bf16x8 ah[4], bh[4], al[4], bl[4];
#pragma unroll
        for (int mb = 0; mb < 4; ++mb) {
            int off = (wm + mb * 16 + lr) * 32 + lkp;
            ah[mb] = *(const bf16x8*)(sA0 + off);
            if (SPLIT) al[mb] = *(const bf16x8*)(sA1 + off);
        }
#pragma unroll
        for (int nb = 0; nb < 4; ++nb) {
            int off = (wn + nb * 16 + lr) * 32 + lkp;
            bh[nb] = *(const bf16x8*)(sB0 + off);
            if (SPLIT) bl[nb] = *(const bf16x8*)(sB1 + off);
        }
#pragma unroll
        for (int mb = 0; mb < 4; ++mb)
#pragma unroll
            for (int nb = 0; nb < 4; ++nb) {
                acc[mb][nb] = __builtin_amdgcn_mfma_f32_16x16x32_bf16(ah[mb], bh[nb], acc[mb][nb], 0, 0, 0);
                if (SPLIT) {
                    acc[mb][nb] = __builtin_amdgcn_mfma_f32_16x16x32_bf16(ah[mb], bl[nb], acc[mb][nb], 0, 0, 0);
                    acc[mb][nb] = __builtin_amdgcn_mfma_f32_16x16x32_bf16(al[mb], bh[nb], acc[mb][nb], 0, 0, 0);
                }
            }
        __syncthreads();
    }

    // epilogue: C/D frag mapping col = l&15, row = (l>>4)*4 + reg  [m89-verified]
    float*  Cfb = Cf  ? (Cf  + (long)bz * sCb) : nullptr;
    ushort* Chb = Chi ? (Chi + (long)bz * sCb) : nullptr;
    ushort* Clb = Clo ? (Clo + (long)bz * sCb) : nullptr;
    const int mrow = (l >> 4) * 4;
#pragma unroll
    for (int nb = 0; nb < 4; ++nb) {
        long n = n0 + wn + nb * 16 + lr;
        float bv = 0.f;
        if (OUTMODE == 1 || OUTMODE == 3) bv = bias[n];
        if (OUTMODE == 2) { if (bias) bv = bias[n]; }
#pragma unroll
        for (int mb = 0; mb < 4; ++mb) {
            long mbase = m0 + wm + mb * 16 + mrow;
#pragma unroll
            for (int r = 0; r < 4; ++r) {
                float x = acc[mb][nb][r] + bv;
                long idx = (mbase + r) * ldc + n;
                if (OUTMODE == 3) {
                    Cfb[idx] = tanhf(x);
                } else if (OUTMODE == 2) {
                    ushort h = f2bf(x);
                    Chb[idx] = h;
                    Clb[idx] = f2bf(x - bf2f(h));
                } else {
                    Cfb[idx] = x;
                }
            }
        }
    }
}

// ---------------------------------------------------------------------------
// Elementwise f32 -> (hi, lo) bf16 pair
// ---------------------------------------------------------------------------
__global__ __launch_bounds__(256) void split_pair_k(
    const float* __restrict__ in, ushort* __restrict__ hi, ushort* __restrict__ lo, long n4)
{
    long i = (long)blockIdx.x * 256 + threadIdx.x;
    const long stride = (long)gridDim.x * 256;
    for (; i < n4; i += stride) {
        float4 x = ((const float4*)in)[i];
        ushort4 h, lw;
        h.x = f2bf(x.x); lw.x = f2bf(x.x - bf2f(h.x));
        h.y = f2bf(x.y); lw.y = f2bf(x.y - bf2f(h.y));
        h.z = f2bf(x.z); lw.z = f2bf(x.z - bf2f(h.z));
        h.w = f2bf(x.w); lw.w = f2bf(x.w - bf2f(h.w));
        ((ushort4*)hi)[i] = h;
        ((ushort4*)lo)[i] = lw;
    }
}

// ---------------------------------------------------------------------------
// values [2048][32][1024] f32 -> per batch-group:
//   vhi/vlo [(s*gc+bi)][1024] bf16 pair  (K2 B-operand, NT)
//   vT [bi][1024][2048] bf16             (K4 B-operand, NT)
// ---------------------------------------------------------------------------
__global__ __launch_bounds__(256) void values_conv_k(
    const float* __restrict__ values,
    ushort* __restrict__ vhi, ushort* __restrict__ vlo, ushort* __restrict__ vT,
    int b0, int gc)
{
    __shared__ float tile[64][65];
    const int t  = threadIdx.x;
    const int s0 = blockIdx.x * 64;
    const int v0 = blockIdx.y * 64;
    const int bi = blockIdx.z;
    const int b  = b0 + bi;
#pragma unroll
    for (int i = 0; i < 4; ++i) {
        int c = t + i * 256;
        int r = c >> 4;
        int qq = c & 15;
        float4 x = *(const float4*)(values + ((long)(s0 + r) * 32 + b) * 1024 + v0 + qq * 4);
        ushort4 h, lw;
        h.x = f2bf(x.x); lw.x = f2bf(x.x - bf2f(h.x));
        h.y = f2bf(x.y); lw.y = f2bf(x.y - bf2f(h.y));
        h.z = f2bf(x.z); lw.z = f2bf(x.z - bf2f(h.z));
        h.w = f2bf(x.w); lw.w = f2bf(x.w - bf2f(h.w));
        long rowoff = ((long)(s0 + r) * gc + bi) * 1024 + v0 + qq * 4;
        *(ushort4*)(vhi + rowoff) = h;
        *(ushort4*)(vlo + rowoff) = lw;
        tile[r][qq * 4 + 0] = x.x;
        tile[r][qq * 4 + 1] = x.y;
        tile[r][qq * 4 + 2] = x.z;
        tile[r][qq * 4 + 3] = x.w;
    }
    __syncthreads();
    const int vr = t >> 2;
    const int ss = (t & 3) * 16;
    ushort* dst = vT + ((long)bi * 1024 + v0 + vr) * 2048 + s0 + ss;
#pragma unroll
    for (int j = 0; j < 4; ++j) {
        ushort4 o;
        o.x = f2bf(tile[ss + j * 4 + 0][vr]);
        o.y = f2bf(tile[ss + j * 4 + 1][vr]);
        o.z = f2bf(tile[ss + j * 4 + 2][vr]);
        o.w = f2bf(tile[ss + j * 4 + 3][vr]);
        *(ushort4*)(dst + j * 4) = o;
    }
}

// softmax over 2048-rows, f32 in -> bf16 P out. One 256-thread block per row.
__global__ __launch_bounds__(256) void softmax2048b_k(
    const float* __restrict__ S, ushort* __restrict__ P)
{
    __shared__ float red[4];
    const long row = blockIdx.x;
    const float* p = S + row * 2048 + threadIdx.x * 8;
    float4 a = ((const float4*)p)[0];
    float4 b = ((const float4*)p)[1];

    float m = fmaxf(fmaxf(fmaxf(a.x, a.y), fmaxf(a.z, a.w)),
                    fmaxf(fmaxf(b.x, b.y), fmaxf(b.z, b.w)));
#pragma unroll
    for (int off = 32; off; off >>= 1) m = fmaxf(m, __shfl_xor(m, off));
    int wid = threadIdx.x >> 6;
    if ((threadIdx.x & 63) == 0) red[wid] = m;
    __syncthreads();
    m = fmaxf(fmaxf(red[0], red[1]), fmaxf(red[2], red[3]));
    __syncthreads();

    a.x = __expf(a.x - m); a.y = __expf(a.y - m);
    a.z = __expf(a.z - m); a.w = __expf(a.w - m);
    b.x = __expf(b.x - m); b.y = __expf(b.y - m);
    b.z = __expf(b.z - m); b.w = __expf(b.w - m);

    float s = a.x + a.y + a.z + a.w + b.x + b.y + b.z + b.w;
#pragma unroll
    for (int off = 32; off; off >>= 1) s += __shfl_xor(s, off);
    if ((threadIdx.x & 63) == 0) red[wid] = s;
    __syncthreads();
    s = red[0] + red[1] + red[2] + red[3];
    float inv = 1.0f / s;

    ushort* qp = P + row * 2048 + threadIdx.x * 8;
    ushort4 oA, oB;
    oA.x = f2bf(a.x * inv); oA.y = f2bf(a.y * inv);
    oA.z = f2bf(a.z * inv); oA.w = f2bf(a.w * inv);
    oB.x = f2bf(b.x * inv); oB.y = f2bf(b.y * inv);
    oB.z = f2bf(b.z * inv); oB.w = f2bf(b.w * inv);
    ((ushort4*)qp)[0] = oA;
    ((ushort4*)qp)[1] = oB;
}

// ===========================================================================
// Fallback fp32 path (round-1 kernels, used only if ws_size is too small)
// ===========================================================================
#define BM 128
#define BN 128
#define BK 16

template<bool NT, int MODE>
__global__ __launch_bounds__(256) void gemm_f32(
    const float* __restrict__ A, const float* __restrict__ A2, int Ksplit,
    const float* __restrict__ Bm, const float* __restrict__ bias,
    float* __restrict__ C,
    long lda, long ldb, long ldc, int K,
    long sAb, long sBb, long sCb)
{
    __shared__ float As[BK][BM + 4];
    __shared__ float Bs[BK][BN + 4];

    const int bz = blockIdx.z;
    const float* Ab  = A + (long)bz * sAb;
    const float* A2b = A2 ? (A2 + (long)bz * sAb) : nullptr;
    const float* Bb  = Bm + (long)bz * sBb;
    float*       Cb  = C + (long)bz * sCb;

    const int m0 = blockIdx.y * BM;
    const int n0 = blockIdx.x * BN;
    const int t  = threadIdx.x;
    const int tx = t & 15;
    const int ty = t >> 4;

    float acc[8][8];
#pragma unroll
    for (int i = 0; i < 8; ++i)
#pragma unroll
        for (int j = 0; j < 8; ++j) acc[i][j] = 0.f;

    for (int k0 = 0; k0 < K; k0 += BK) {
        const float* Asrc = (A2b && k0 >= Ksplit) ? (A2b - Ksplit) : Ab;
#pragma unroll
        for (int c = 0; c < 2; ++c) {
            int chunk = t + c * 256;
            int row = chunk >> 2;
            int kq  = chunk & 3;
            float4 v = *(const float4*)(Asrc + (long)(m0 + row) * lda + k0 + kq * 4);
            As[kq * 4 + 0][row] = v.x;
            As[kq * 4 + 1][row] = v.y;
            As[kq * 4 + 2][row] = v.z;
            As[kq * 4 + 3][row] = v.w;
        }
        if (NT) {
#pragma unroll
            for (int c = 0; c < 2; ++c) {
                int chunk = t + c * 256;
                int row = chunk >> 2;
                int kq  = chunk & 3;
                float4 v = *(const float4*)(Bb + (long)(n0 + row) * ldb + k0 + kq * 4);
                Bs[kq * 4 + 0][row] = v.x;
                Bs[kq * 4 + 1][row] = v.y;
                Bs[kq * 4 + 2][row] = v.z;
                Bs[kq * 4 + 3][row] = v.w;
            }
        } else {
#pragma unroll
            for (int c = 0; c < 2; ++c) {
                int chunk = t + c * 256;
                int kr = chunk >> 5;
                int vq = chunk & 31;
                float4 v = *(const float4*)(Bb + (long)(k0 + kr) * ldb + n0 + vq * 4);
                *(float4*)&Bs[kr][vq * 4] = v;
            }
        }
        __syncthreads();

#pragma unroll
        for (int k = 0; k < BK; ++k) {
            float4 a0 = *(const float4*)&As[k][ty * 8];
            float4 a1 = *(const float4*)&As[k][ty * 8 + 4];
            float4 b0 = *(const float4*)&Bs[k][tx * 8];
            float4 b1 = *(const float4*)&Bs[k][tx * 8 + 4];
            float ar[8] = {a0.x, a0.y, a0.z, a0.w, a1.x, a1.y, a1.z, a1.w};
            float br[8] = {b0.x, b0.y, b0.z, b0.w, b1.x, b1.y, b1.z, b1.w};
#pragma unroll
            for (int i = 0; i < 8; ++i)
#pragma unroll
                for (int j = 0; j < 8; ++j)
                    acc[i][j] += ar[i] * br[j];
        }
        __syncthreads();
    }

    float brow[8];
    if (MODE >= 1) {
#pragma unroll
        for (int j = 0; j < 8; ++j) brow[j] = bias[n0 + tx * 8 + j];
    }
#pragma unroll
    for (int i = 0; i < 8; ++i) {
        long row = m0 + ty * 8 + i;
        float v[8];
#pragma unroll
        for (int j = 0; j < 8; ++j) {
            float x = acc[i][j];
            if (MODE >= 1) x += brow[j];
            if (MODE == 2) x = tanhf(x);
            v[j] = x;
        }
        float4* dst = (float4*)&Cb[row * ldc + n0 + tx * 8];
        dst[0] = make_float4(v[0], v[1], v[2], v[3]);
        dst[1] = make_float4(v[4], v[5], v[6], v[7]);
    }
}

__global__ __launch_bounds__(256) void softmax2048(float* __restrict__ S)
{
    __shared__ float red[4];
    float* p = S + (long)blockIdx.x * 2048 + threadIdx.x * 8;
    float4 a = ((float4*)p)[0];
    float4 b = ((float4*)p)[1];

    float m = fmaxf(fmaxf(fmaxf(a.x, a.y), fmaxf(a.z, a.w)),
                    fmaxf(fmaxf(b.x, b.y), fmaxf(b.z, b.w)));
#pragma unroll
    for (int off = 32; off; off >>= 1) m = fmaxf(m, __shfl_xor(m, off));
    int wid = threadIdx.x >> 6;
    if ((threadIdx.x & 63) == 0) red[wid] = m;
    __syncthreads();
    m = fmaxf(fmaxf(red[0], red[1]), fmaxf(red[2], red[3]));
    __syncthreads();

    a.x = __expf(a.x - m); a.y = __expf(a.y - m);
    a.z = __expf(a.z - m); a.w = __expf(a.w - m);
    b.x = __expf(b.x - m); b.y = __expf(b.y - m);
    b.z = __expf(b.z - m); b.w = __expf(b.w - m);

    float s = a.x + a.y + a.z + a.w + b.x + b.y + b.z + b.w;
#pragma unroll
    for (int off = 32; off; off >>= 1) s += __shfl_xor(s, off);
    if ((threadIdx.x & 63) == 0) red[wid] = s;
    __syncthreads();
    s = red[0] + red[1] + red[2] + red[3];
    float inv = 1.0f / s;

    a.x *= inv; a.y *= inv; a.z *= inv; a.w *= inv;
    b.x *= inv; b.y *= inv; b.z *= inv; b.w *= inv;
    ((float4*)p)[0] = a;
    ((float4*)p)[1] = b;
}

// ===========================================================================
extern "C" void kernel_launch(void* const* d_in, const int* in_sizes, int n_in,
                              void* d_out, int out_size, void* d_ws, size_t ws_size,
                              hipStream_t stream)
{
    const float* query  = (const float*)d_in[0];
    const float* values = (const float*)d_in[1];
    const float* W1     = (const float*)d_in[2];
    const float* b1     = (const float*)d_in[3];
    const float* W2     = (const float*)d_in[4];
    const float* b2     = (const float*)d_in[5];
    float* out = (float*)d_out;

    const int Bc = 32, QL = 512, SL = 2048, D = 1024, F = 2048;
    const long R = (long)QL * Bc;   // 16384

    char* p = (char*)d_ws;
    auto take = [&](size_t bytes) -> char* {
        char* r = p;
        p += (bytes + 255) & ~(size_t)255;
        return r;
    };

    ushort* q_hi  = (ushort*)take((size_t)R * D * 2);
    ushort* q_lo  = (ushort*)take((size_t)R * D * 2);
    ushort* w1_hi = (ushort*)take((size_t)D * D * 2);
    ushort* w1_lo = (ushort*)take((size_t)D * D * 2);
    ushort* w2_hi = (ushort*)take((size_t)D * F * 2);
    ushort* w2_lo = (ushort*)take((size_t)D * F * 2);
    ushort* qr_hi = (ushort*)take((size_t)R * D * 2);
    ushort* qr_lo = (ushort*)take((size_t)R * D * 2);
    ushort* at_hi = (ushort*)take((size_t)R * D * 2);
    ushort* at_lo = (ushort*)take((size_t)R * D * 2);
    size_t fixedBytes = (size_t)(p - (char*)d_ws);

    // per batch: vals hi+lo+vT (3 * 4 MB) + scores f32 (4 MB) + P bf16 (2 MB)
    const size_t perBatch = (size_t)SL * D * 2 * 3 + (size_t)QL * SL * 4 + (size_t)QL * SL * 2 + 2048;
    long availB = (long)ws_size - (long)fixedBytes;
    int g = availB > 0 ? (int)(availB / (long)perBatch) : 0;
    if (g > 32) g = 32;

    if (g >= 1) {
        // ----------------------- fast split-bf16 MFMA path -----------------
        ushort* vals_hi = (ushort*)take((size_t)SL * D * 2 * g);
        ushort* vals_lo = (ushort*)take((size_t)SL * D * 2 * g);
        ushort* vT      = (ushort*)take((size_t)SL * D * 2 * g);
        float*  scores  = (float*) take((size_t)QL * SL * 4 * g);
        ushort* P       = (ushort*)take((size_t)QL * SL * 2 * g);

        split_pair_k<<<2048, 256, 0, stream>>>(query, q_hi, q_lo, R * D / 4);
        split_pair_k<<<1024, 256, 0, stream>>>(W1, w1_hi, w1_lo, (long)D * D / 4);
        split_pair_k<<<1024, 256, 0, stream>>>(W2, w2_hi, w2_lo, (long)D * F / 4);

        // K1: qr = query.W1^T + b1   -> bf16 pair
        gemm_bf16_mfma<true, false, 2><<<dim3(D / 128, R / 128, 1), 256, 0, stream>>>(
            q_hi, q_lo, nullptr, nullptr, 1 << 30,
            w1_hi, w1_lo, b1,
            nullptr, qr_hi, qr_lo,
            D, D, D, D, 0, 0, 0);

        for (int b0 = 0; b0 < Bc; b0 += g) {
            int gc = (Bc - b0 < g) ? (Bc - b0) : g;

            values_conv_k<<<dim3(SL / 64, D / 64, gc), 256, 0, stream>>>(
                values, vals_hi, vals_lo, vT, b0, gc);

            // K2: scores[bi,q,s] = qr[q*32+b,:] . values[s*32+b,:]
            gemm_bf16_mfma<true, false, 0><<<dim3(SL / 128, QL / 128, gc), 256, 0, stream>>>(
                qr_hi + (size_t)b0 * D, qr_lo + (size_t)b0 * D, nullptr, nullptr, 1 << 30,
                vals_hi, vals_lo, nullptr,
                scores, nullptr, nullptr,
                (long)Bc * D, (long)gc * D, SL, D,
                D, D, (long)QL * SL);

            softmax2048b_k<<<gc * QL, 256, 0, stream>>>(scores, P);

            // K4: att[q*32+b, v] = sum_s P[bi,q,s] * vT[bi,v,s]   -> bf16 pair
            gemm_bf16_mfma<false, false, 2><<<dim3(D / 128, QL / 128, gc), 256, 0, stream>>>(
                P, nullptr, nullptr, nullptr, 1 << 30,
                vT, nullptr, nullptr,
                nullptr, at_hi + (size_t)b0 * D, at_lo + (size_t)b0 * D,
                SL, SL, (long)Bc * D, SL,
                (long)QL * SL, (long)D * SL, D);
        }

        // K5: out = tanh([att, query] . W2^T + b2)
        gemm_bf16_mfma<true, true, 3><<<dim3(D / 128, R / 128, 1), 256, 0, stream>>>(
            at_hi, at_lo, q_hi, q_lo, D,
            w2_hi, w2_lo, b2,
            out, nullptr, nullptr,
            D, F, D, F, 0, 0, 0);
        return;
    }

    // ----------------------- fp32 fallback (round-1) -----------------------
    float* qr = (float*)d_ws;
    size_t qrBytes = (size_t)R * D * sizeof(float);
    float* sc = (float*)((char*)d_ws + qrBytes);
    size_t scPerB = (size_t)QL * SL * sizeof(float);

    int grp = 32;
    if (ws_size < qrBytes + 32 * scPerB) {
        size_t avail = ws_size > qrBytes ? ws_size - qrBytes : 0;
        grp = (int)(avail / scPerB);
        if (grp < 1)  grp = 1;
        if (grp > 32) grp = 32;
    }

    {
        dim3 gd(D / BN, R / BM, 1);
        gemm_f32<true, 1><<<gd, 256, 0, stream>>>(
            query, nullptr, 1 << 30, W1, b1, qr,
            D, D, D, D, 0, 0, 0);
    }
    for (int b0 = 0; b0 < Bc; b0 += grp) {
        int gg = (Bc - b0 < grp) ? (Bc - b0) : grp;
        {
            dim3 gd(SL / BN, QL / BM, gg);
            gemm_f32<true, 0><<<gd, 256, 0, stream>>>(
                qr + (size_t)b0 * D, nullptr, 1 << 30,
                values + (size_t)b0 * D, nullptr, sc,
                (long)Bc * D, (long)Bc * D, SL, D,
                D, D, (long)QL * SL);
        }
        softmax2048<<<gg * QL, 256, 0, stream>>>(sc);
        {
            dim3 gd(D / BN, QL / BM, gg);
            gemm_f32<false, 0><<<gd, 256, 0, stream>>>(
                sc, nullptr, 1 << 30,
                values + (size_t)b0 * D, nullptr, qr + (size_t)b0 * D,
                SL, (long)Bc * D, (long)Bc * D, SL,
                (long)QL * SL, D, D);
        }
    }
    {
        dim3 gd(D / BN, R / BM, 1);
        gemm_f32<true, 2><<<gd, 256, 0, stream>>>(
            qr, query, D, W2, b2, out,
            D, 2048, D, 2048, 0, 0, 0);
    }
}